// Round 5
// baseline (263.602 us; speedup 1.0000x reference)
//
#include <hip/hip_runtime.h>
#include <math.h>

// Problem constants (fixed by setup_inputs)
constexpr int B  = 4;
constexpr int N  = 512;
constexpr int D  = 64;
constexpr int O  = 64;
constexpr int NK = 256;   // n_keep = N * 0.5

#define TEMP_INV   0.5f
#define BN_EPS     1e-5f
#define SELU_SCALE 1.0507009873554805f
#define SELU_ALPHA 1.6732632423543772f

// tanh(x) = 1 - 2/(exp(2x)+1). Clamp: tanh saturates to fp32 ±1 by |x|~9.
__device__ __forceinline__ float fast_tanh(float x) {
    x = fminf(9.f, fmaxf(-9.f, x));
    const float e = __expf(2.f * x);
    return 1.f - 2.f / (e + 1.f);
}

// ---------------------------------------------------------------------------
// Kernel 1: pair logits via symmetry (logits[i][j]==logits[j][i]).
// Block (b,k) owns rows i0=k (k strict pairs) and i1=N-1-k (511-k pairs).
// k2 = ceil(k/2). Threads [0,k2): two consecutive i0-pairs (j=2t, 2t+1).
// Threads [k2,256): two consecutive i1-pairs. One dummy pair per block; every
// thread uses ONE folded-weight base -> each broadcast ds_read_b128 feeds 8
// FMAs (VALU-bound). Epilogue: waves 0/1 compute the two diagonal logits.
// Writes logits*TEMP_INV to lws[b][row][j] and lws[b][j][row] (full matrix).
// ---------------------------------------------------------------------------
__global__ __launch_bounds__(256, 2) void aasist_pair_kernel(
    const float* __restrict__ x,      // [B,N,D]
    const float* __restrict__ attW,   // [D,O]
    const float* __restrict__ attB,   // [O]
    const float* __restrict__ attV,   // [O]
    float* __restrict__ lws)          // [B,N,N]
{
    __shared__ float sW0[D][O];   // x_i0[d] * attW[d][o]
    __shared__ float sW1[D][O];   // x_i1[d] * attW[d][o]
    __shared__ float sX0[D];
    __shared__ float sX1[D];
    __shared__ float sAb[O];
    __shared__ float sAw[O];

    const int tid = threadIdx.x;
    const int blk = blockIdx.x;
    const int b   = blk >> 8;
    const int k   = blk & 255;
    const int i0  = k;
    const int i1  = N - 1 - k;

    const float* xb = x + (size_t)b * N * D;
    const float* x0 = xb + (size_t)i0 * D;
    const float* x1 = xb + (size_t)i1 * D;

    for (int t = tid; t < D * O; t += 256) {
        const int d = t >> 6;
        const float w = attW[t];
        sW0[0][t] = x0[d] * w;     // flat index == t
        sW1[0][t] = x1[d] * w;
    }
    if (tid < D) { sX0[tid] = x0[tid]; sX1[tid] = x1[tid]; }
    if (tid < O) { sAb[tid] = attB[tid]; sAw[tid] = attV[tid]; }
    __syncthreads();

    const int  k2   = (k + 1) >> 1;
    const bool isI0 = (tid < k2);
    const int  p0   = isI0 ? 2 * tid : 2 * (tid - k2);   // pair index = j
    const int  p1   = p0 + 1;
    const int  row  = isI0 ? i0 : i1;
    const int  lim  = isI0 ? k : (N - 1 - k);            // j valid iff j < lim
    const bool v0   = (p0 < lim);
    const bool v1   = (p1 < lim);

    const float* wb   = isI0 ? &sW0[0][0] : &sW1[0][0];  // ONE base per thread
    const float* xj0p = xb + (size_t)p0 * D;             // p0,p1 always < N
    const float* xj1p = xb + (size_t)p1 * D;

    float logit0 = 0.f, logit1 = 0.f;

    #pragma unroll
    for (int op = 0; op < 2; ++op) {                // two o-passes of 32
        const int o0 = op * 32;
        float acc0[32], acc1[32];
        #pragma unroll
        for (int o = 0; o < 32; ++o) { acc0[o] = 0.f; acc1[o] = 0.f; }

        for (int dc = 0; dc < D; dc += 16) {        // d in chunks of 16
            float xj0[16], xj1[16];
            #pragma unroll
            for (int q = 0; q < 16; q += 4) {
                *(float4*)&xj0[q] = *(const float4*)&xj0p[dc + q];
                *(float4*)&xj1[q] = *(const float4*)&xj1p[dc + q];
            }
            #pragma unroll
            for (int dd = 0; dd < 16; ++dd) {
                const int d = dc + dd;
                const float a0 = xj0[dd];
                const float a1 = xj1[dd];
                #pragma unroll
                for (int o = 0; o < 32; o += 4) {
                    const float4 w = *(const float4*)&wb[d * O + o0 + o]; // broadcast
                    acc0[o]   += a0 * w.x; acc0[o+1] += a0 * w.y;
                    acc0[o+2] += a0 * w.z; acc0[o+3] += a0 * w.w;
                    acc1[o]   += a1 * w.x; acc1[o+1] += a1 * w.y;
                    acc1[o+2] += a1 * w.z; acc1[o+3] += a1 * w.w;
                }
            }
        }
        #pragma unroll
        for (int o = 0; o < 32; ++o) {
            const float bo = sAb[o0 + o];
            const float vo = sAw[o0 + o];
            logit0 += fast_tanh(acc0[o] + bo) * vo;
            logit1 += fast_tanh(acc1[o] + bo) * vo;
        }
    }
    logit0 *= TEMP_INV;
    logit1 *= TEMP_INV;

    float* Lb = lws + (size_t)b * N * N;
    if (v0) {
        Lb[(size_t)row * N + p0] = logit0;
        Lb[(size_t)p0 * N + row] = logit0;
    }
    if (v1) {
        Lb[(size_t)row * N + p1] = logit1;
        Lb[(size_t)p1 * N + row] = logit1;
    }

    // ---- diagonal logits: wave 0 -> i0, wave 1 -> i1 ----
    if (tid < 128) {
        const int  o    = tid & 63;
        const bool hi   = (tid >= 64);
        const float* wD = hi ? &sW1[0][0] : &sW0[0][0];
        const float* xD = hi ? sX1 : sX0;
        float acc = 0.f;
        #pragma unroll 16
        for (int d = 0; d < D; ++d)
            acc += xD[d] * wD[d * O + o];   // lane o -> bank o%32: 2-way, free
        float t = fast_tanh(acc + sAb[o]) * sAw[o];
        #pragma unroll
        for (int s = 32; s > 0; s >>= 1) t += __shfl_xor(t, s);
        if (o == 0) {
            const int ii = hi ? i1 : i0;
            Lb[(size_t)ii * N + ii] = t * TEMP_INV;
        }
    }
}

// ---------------------------------------------------------------------------
// Kernel 2: per (b,i) row — softmax over the stored logit row, aggregation,
// dual projection, BN(eval), SELU, sigmoid pool score.
// ---------------------------------------------------------------------------
__global__ __launch_bounds__(256, 2) void aasist_row_kernel(
    const float* __restrict__ x,      // [B,N,D]
    const float* __restrict__ pAw,    // [D,O]
    const float* __restrict__ pAb,    // [O]
    const float* __restrict__ pNw,    // [D,O]
    const float* __restrict__ pNb,    // [O]
    const float* __restrict__ bng, const float* __restrict__ bnb,
    const float* __restrict__ bnm, const float* __restrict__ bnv,
    const float* __restrict__ poolW,  // [O]
    const float* __restrict__ poolB,  // [1]
    const float* __restrict__ lws,    // [B,N,N] (logits * TEMP_INV, complete)
    float* __restrict__ h_out,        // [B,N,O]
    float* __restrict__ s_out)        // [B,N]
{
    __shared__ float sXi[D];
    __shared__ float sAtt[N];
    __shared__ float sRed[256];
    __shared__ float sAgg[D];
    __shared__ float sH[O];

    const int tid = threadIdx.x;
    const int blk = blockIdx.x;
    const int b   = blk >> 9;
    const int i   = blk & (N - 1);

    const float* xb = x + (size_t)b * N * D;
    const float* xi = xb + (size_t)i * D;

    if (tid < D) sXi[tid] = xi[tid];   // first read is after several barriers

    const float* Lrow = lws + ((size_t)b * N + i) * N;
    const float logit0 = Lrow[tid];
    const float logit1 = Lrow[tid + 256];

    // ---- softmax over j (block-wide, 512 values) ----
    float m = fmaxf(logit0, logit1);
    #pragma unroll
    for (int s = 32; s > 0; s >>= 1) m = fmaxf(m, __shfl_xor(m, s));
    if ((tid & 63) == 0) sRed[tid >> 6] = m;
    __syncthreads();
    const float mAll = fmaxf(fmaxf(sRed[0], sRed[1]), fmaxf(sRed[2], sRed[3]));

    const float e0 = __expf(logit0 - mAll);
    const float e1 = __expf(logit1 - mAll);
    float ssum = e0 + e1;
    #pragma unroll
    for (int s = 32; s > 0; s >>= 1) ssum += __shfl_xor(ssum, s);
    if ((tid & 63) == 0) sRed[4 + (tid >> 6)] = ssum;
    __syncthreads();
    const float inv = 1.f / (sRed[4] + sRed[5] + sRed[6] + sRed[7]);
    sAtt[tid]       = e0 * inv;
    sAtt[tid + 256] = e1 * inv;
    __syncthreads();

    // ---- agg[d] = sum_j att[j] * x[b,j,d] ----
    {
        const int d = tid & 63;
        const int g = tid >> 6;              // 4 j-ranges of 128
        float p = 0.f;
        const int jlo = g * 128, jhi = jlo + 128;
        for (int j = jlo; j < jhi; ++j)
            p += sAtt[j] * xb[(size_t)j * D + d];   // coalesced across lanes
        sRed[tid] = p;
        __syncthreads();
        if (tid < 64)
            sAgg[tid] = sRed[tid] + sRed[tid + 64] + sRed[tid + 128] + sRed[tid + 192];
        __syncthreads();
    }

    // ---- h = agg@pAw + pAb + xi@pNw + pNb; BN; SELU; score ----
    {
        const int o = tid & 63;
        const int g = tid >> 6;              // 4 d-ranges of 16
        float p = 0.f;
        #pragma unroll
        for (int dd = 0; dd < 16; ++dd) {
            const int d = g * 16 + dd;
            p += sAgg[d] * pAw[d * O + o] + sXi[d] * pNw[d * O + o];
        }
        sRed[tid] = p;
        __syncthreads();
        if (tid < 64) {
            float hv = sRed[tid] + sRed[tid + 64] + sRed[tid + 128] + sRed[tid + 192]
                     + pAb[tid] + pNb[tid];
            hv = (hv - bnm[tid]) * rsqrtf(bnv[tid] + BN_EPS) * bng[tid] + bnb[tid];
            hv = hv > 0.f ? SELU_SCALE * hv
                          : SELU_SCALE * SELU_ALPHA * (__expf(hv) - 1.f);
            sH[tid] = hv;
            h_out[((size_t)b * N + i) * O + tid] = hv;
        }
        __syncthreads();
    }
    if (tid < 64) {
        float v = sH[tid] * poolW[tid];
        #pragma unroll
        for (int s = 32; s > 0; s >>= 1) v += __shfl_xor(v, s);
        if (tid == 0)
            s_out[b * N + i] = 1.f / (1.f + __expf(-(v + poolB[0])));
    }
}

// ---------------------------------------------------------------------------
// Kernel 3: exact top-k (value desc, index asc ties — matches jax.lax.top_k)
// via O(N^2) ranking, then coalesced weighted gather.
// ---------------------------------------------------------------------------
__global__ __launch_bounds__(256) void aasist_topk_kernel(
    const float* __restrict__ h,   // [B,N,O]
    const float* __restrict__ s,   // [B,N]
    float* __restrict__ out)       // [B,NK,O]
{
    __shared__ float ss[N];
    __shared__ int   sel[NK];
    const int b   = blockIdx.x;
    const int tid = threadIdx.x;

    ss[tid]       = s[b * N + tid];
    ss[tid + 256] = s[b * N + tid + 256];
    __syncthreads();

    #pragma unroll
    for (int jj = 0; jj < 2; ++jj) {
        const int   j = tid + jj * 256;
        const float v = ss[j];
        int rank = 0;
        for (int kk = 0; kk < N; ++kk) {
            const float u = ss[kk];
            rank += (u > v) || (u == v && kk < j);
        }
        if (rank < NK) sel[rank] = j;
    }
    __syncthreads();

    #pragma unroll 4
    for (int rep = 0; rep < (NK * O) / 256; ++rep) {
        const int flat = rep * 256 + tid;
        const int kk = flat >> 6;
        const int o  = flat & 63;
        const int j  = sel[kk];
        out[((size_t)b * NK + kk) * O + o] = h[((size_t)b * N + j) * O + o] * ss[j];
    }
}

extern "C" void kernel_launch(void* const* d_in, const int* in_sizes, int n_in,
                              void* d_out, int out_size, void* d_ws, size_t ws_size,
                              hipStream_t stream) {
    const float* x     = (const float*)d_in[0];
    const float* attW  = (const float*)d_in[1];
    const float* attB  = (const float*)d_in[2];
    const float* attV  = (const float*)d_in[3];
    const float* pAw   = (const float*)d_in[4];
    const float* pAb   = (const float*)d_in[5];
    const float* pNw   = (const float*)d_in[6];
    const float* pNb   = (const float*)d_in[7];
    const float* bng   = (const float*)d_in[8];
    const float* bnb   = (const float*)d_in[9];
    const float* bnm   = (const float*)d_in[10];
    const float* bnv   = (const float*)d_in[11];
    const float* poolW = (const float*)d_in[12];
    const float* poolB = (const float*)d_in[13];
    float* out = (float*)d_out;

    float* l_ws = (float*)d_ws;                     // B*N*N floats (4 MB)
    float* h_ws = l_ws + (size_t)B * N * N;         // B*N*O floats
    float* s_ws = h_ws + (size_t)B * N * O;         // B*N floats

    aasist_pair_kernel<<<B * 256, 256, 0, stream>>>(x, attW, attB, attV, l_ws);

    aasist_row_kernel<<<B * N, 256, 0, stream>>>(
        x, pAw, pAb, pNw, pNb,
        bng, bnb, bnm, bnv, poolW, poolB, l_ws, h_ws, s_ws);

    aasist_topk_kernel<<<B, 256, 0, stream>>>(h_ws, s_ws, out);
}

// Round 6
// 210.148 us; speedup vs baseline: 1.2544x; 1.2544x over previous
//
#include <hip/hip_runtime.h>
#include <math.h>

// Problem constants (fixed by setup_inputs)
constexpr int B  = 4;
constexpr int N  = 512;
constexpr int D  = 64;
constexpr int O  = 64;
constexpr int NK = 256;   // n_keep = N * 0.5

#define TEMP_INV   0.5f
#define BN_EPS     1e-5f
#define SELU_SCALE 1.0507009873554805f
#define SELU_ALPHA 1.6732632423543772f

// tanh(x) = 1 - 2/(exp(2x)+1). Clamp: tanh saturates to fp32 ±1 by |x|~9.
__device__ __forceinline__ float fast_tanh(float x) {
    x = fminf(9.f, fmaxf(-9.f, x));
    const float e = __expf(2.f * x);
    return 1.f - 2.f / (e + 1.f);
}

// ---------------------------------------------------------------------------
// Kernel 1: pair logits via symmetry (logits[i][j]==logits[j][i]).
// Block (b,k), 512 threads, ONE pair per thread, ONE o-pass (acc[64]).
// Rows i0=k (k strict-lower pairs) and i1=N-1-k (511-k strict-lower pairs):
//   t in [0,k)   : row=i0, j=t        (j<i0)
//   t in [k,512) : row=i1, j=t-k      (j<i1; t=511 -> j=i1 = i1's DIAGONAL)
// Stores ONLY Lb[row*N+j] (coalesced row segments; strict lower + i1 diag).
// Epilogue wave computes i0's diagonal. NO transpose mirror writes (the round-4
// version's 4B scatter caused 264 MB of RFO/writeback traffic).
// ---------------------------------------------------------------------------
__global__ __launch_bounds__(512, 4) void aasist_pair_kernel(
    const float* __restrict__ x,      // [B,N,D]
    const float* __restrict__ attW,   // [D,O]
    const float* __restrict__ attB,   // [O]
    const float* __restrict__ attV,   // [O]
    float* __restrict__ lws)          // [B,N,N]
{
    __shared__ float sW0[D * O];  // x_i0[d] * attW[d][o]
    __shared__ float sW1[D * O];  // x_i1[d] * attW[d][o]
    __shared__ float sX0[D];
    __shared__ float sAb[O];
    __shared__ float sAw[O];

    const int tid = threadIdx.x;
    const int blk = blockIdx.x;
    const int b   = blk >> 8;
    const int k   = blk & 255;
    const int i0  = k;
    const int i1  = N - 1 - k;

    const float* xb = x + (size_t)b * N * D;
    const float* x0 = xb + (size_t)i0 * D;
    const float* x1 = xb + (size_t)i1 * D;

    for (int t = tid; t < D * O; t += 512) {
        const int d = t >> 6;
        const float w = attW[t];
        sW0[t] = x0[d] * w;
        sW1[t] = x1[d] * w;
    }
    if (tid < D) sX0[tid] = x0[tid];
    if (tid < O) { sAb[tid] = attB[tid]; sAw[tid] = attV[tid]; }
    __syncthreads();

    const bool isI0 = (tid < k);
    const int  row  = isI0 ? i0 : i1;
    const int  j    = isI0 ? tid : tid - k;      // j <= 511; t=511 -> j=i1 (diag)
    const float* wb = isI0 ? sW0 : sW1;          // ONE folded-weight base/thread
    const float* xjp = xb + (size_t)j * D;

    float acc[64];
    #pragma unroll
    for (int o = 0; o < 64; ++o) acc[o] = 0.f;

    for (int dc = 0; dc < D; dc += 16) {         // d in chunks of 16
        float xj[16];
        #pragma unroll
        for (int q = 0; q < 16; q += 4)
            *(float4*)&xj[q] = *(const float4*)&xjp[dc + q];
        #pragma unroll
        for (int dd = 0; dd < 16; ++dd) {
            const float a = xj[dd];
            const float* wrow = &wb[(dc + dd) * O];
            #pragma unroll
            for (int o = 0; o < 64; o += 4) {
                const float4 w = *(const float4*)&wrow[o];   // broadcast ds_read
                acc[o]     += a * w.x;
                acc[o + 1] += a * w.y;
                acc[o + 2] += a * w.z;
                acc[o + 3] += a * w.w;
            }
        }
    }

    float logit = 0.f;
    #pragma unroll
    for (int o = 0; o < 64; ++o)
        logit += fast_tanh(acc[o] + sAb[o]) * sAw[o];
    logit *= TEMP_INV;

    float* Lb = lws + (size_t)b * N * N;
    Lb[(size_t)row * N + j] = logit;             // coalesced row segments

    // ---- epilogue: i0's diagonal (wave 0) ----
    if (tid < 64) {
        const int o = tid;
        float a = 0.f;
        #pragma unroll 16
        for (int d = 0; d < D; ++d)
            a += sX0[d] * sW0[d * O + o];        // bank o%32: 2-way, free
        float t = fast_tanh(a + sAb[o]) * sAw[o];
        #pragma unroll
        for (int s = 32; s > 0; s >>= 1) t += __shfl_xor(t, s);
        if (o == 0) Lb[(size_t)i0 * N + i0] = t * TEMP_INV;
    }
}

// ---------------------------------------------------------------------------
// Kernel 2: per (b,i) row — gather logit row (lower triangle direct, upper via
// column read), softmax, aggregation, dual projection, BN(eval), SELU, score.
// ---------------------------------------------------------------------------
__global__ __launch_bounds__(256, 4) void aasist_row_kernel(
    const float* __restrict__ x,      // [B,N,D]
    const float* __restrict__ pAw,    // [D,O]
    const float* __restrict__ pAb,    // [O]
    const float* __restrict__ pNw,    // [D,O]
    const float* __restrict__ pNb,    // [O]
    const float* __restrict__ bng, const float* __restrict__ bnb,
    const float* __restrict__ bnm, const float* __restrict__ bnv,
    const float* __restrict__ poolW,  // [O]
    const float* __restrict__ poolB,  // [1]
    const float* __restrict__ lws,    // [B,N,N] strict lower + diag, *TEMP_INV
    float* __restrict__ h_out,        // [B,N,O]
    float* __restrict__ s_out)        // [B,N]
{
    __shared__ float sXi[D];
    __shared__ float sAtt[N];
    __shared__ float sRed[256];
    __shared__ float sAgg[D];
    __shared__ float sH[O];

    const int tid = threadIdx.x;
    const int blk = blockIdx.x;
    const int b   = blk >> 9;
    const int i   = blk & (N - 1);

    const float* xb = x + (size_t)b * N * D;
    const float* xi = xb + (size_t)i * D;

    if (tid < D) sXi[tid] = xi[tid];   // first read is after several barriers

    const float* Lb = lws + (size_t)b * N * N;
    const int j0 = tid, j1 = tid + 256;
    const size_t a0 = (j0 <= i) ? ((size_t)i * N + j0) : ((size_t)j0 * N + i);
    const size_t a1 = (j1 <= i) ? ((size_t)i * N + j1) : ((size_t)j1 * N + i);
    const float logit0 = Lb[a0];
    const float logit1 = Lb[a1];

    // ---- softmax over j (block-wide, 512 values) ----
    float m = fmaxf(logit0, logit1);
    #pragma unroll
    for (int s = 32; s > 0; s >>= 1) m = fmaxf(m, __shfl_xor(m, s));
    if ((tid & 63) == 0) sRed[tid >> 6] = m;
    __syncthreads();
    const float mAll = fmaxf(fmaxf(sRed[0], sRed[1]), fmaxf(sRed[2], sRed[3]));

    const float e0 = __expf(logit0 - mAll);
    const float e1 = __expf(logit1 - mAll);
    float ssum = e0 + e1;
    #pragma unroll
    for (int s = 32; s > 0; s >>= 1) ssum += __shfl_xor(ssum, s);
    if ((tid & 63) == 0) sRed[4 + (tid >> 6)] = ssum;
    __syncthreads();
    const float inv = 1.f / (sRed[4] + sRed[5] + sRed[6] + sRed[7]);
    sAtt[tid]       = e0 * inv;
    sAtt[tid + 256] = e1 * inv;
    __syncthreads();

    // ---- agg[d] = sum_j att[j] * x[b,j,d] ----
    {
        const int d = tid & 63;
        const int g = tid >> 6;              // 4 j-ranges of 128
        float p = 0.f;
        const int jlo = g * 128, jhi = jlo + 128;
        #pragma unroll 8
        for (int j = jlo; j < jhi; ++j)
            p += sAtt[j] * xb[(size_t)j * D + d];   // coalesced across lanes
        sRed[tid] = p;
        __syncthreads();
        if (tid < 64)
            sAgg[tid] = sRed[tid] + sRed[tid + 64] + sRed[tid + 128] + sRed[tid + 192];
        __syncthreads();
    }

    // ---- h = agg@pAw + pAb + xi@pNw + pNb; BN; SELU; score ----
    {
        const int o = tid & 63;
        const int g = tid >> 6;              // 4 d-ranges of 16
        float p = 0.f;
        #pragma unroll
        for (int dd = 0; dd < 16; ++dd) {
            const int d = g * 16 + dd;
            p += sAgg[d] * pAw[d * O + o] + sXi[d] * pNw[d * O + o];
        }
        sRed[tid] = p;
        __syncthreads();
        if (tid < 64) {
            float hv = sRed[tid] + sRed[tid + 64] + sRed[tid + 128] + sRed[tid + 192]
                     + pAb[tid] + pNb[tid];
            hv = (hv - bnm[tid]) * rsqrtf(bnv[tid] + BN_EPS) * bng[tid] + bnb[tid];
            hv = hv > 0.f ? SELU_SCALE * hv
                          : SELU_SCALE * SELU_ALPHA * (__expf(hv) - 1.f);
            sH[tid] = hv;
            h_out[((size_t)b * N + i) * O + tid] = hv;
        }
        __syncthreads();
    }
    if (tid < 64) {
        float v = sH[tid] * poolW[tid];
        #pragma unroll
        for (int s = 32; s > 0; s >>= 1) v += __shfl_xor(v, s);
        if (tid == 0)
            s_out[b * N + i] = 1.f / (1.f + __expf(-(v + poolB[0])));
    }
}

// ---------------------------------------------------------------------------
// Kernel 3: exact top-k (value desc, index asc ties — matches jax.lax.top_k)
// via O(N^2) ranking, then coalesced weighted gather.
// ---------------------------------------------------------------------------
__global__ __launch_bounds__(256) void aasist_topk_kernel(
    const float* __restrict__ h,   // [B,N,O]
    const float* __restrict__ s,   // [B,N]
    float* __restrict__ out)       // [B,NK,O]
{
    __shared__ float ss[N];
    __shared__ int   sel[NK];
    const int b   = blockIdx.x;
    const int tid = threadIdx.x;

    ss[tid]       = s[b * N + tid];
    ss[tid + 256] = s[b * N + tid + 256];
    __syncthreads();

    #pragma unroll
    for (int jj = 0; jj < 2; ++jj) {
        const int   j = tid + jj * 256;
        const float v = ss[j];
        int rank = 0;
        for (int kk = 0; kk < N; ++kk) {
            const float u = ss[kk];
            rank += (u > v) || (u == v && kk < j);
        }
        if (rank < NK) sel[rank] = j;
    }
    __syncthreads();

    #pragma unroll 4
    for (int rep = 0; rep < (NK * O) / 256; ++rep) {
        const int flat = rep * 256 + tid;
        const int kk = flat >> 6;
        const int o  = flat & 63;
        const int j  = sel[kk];
        out[((size_t)b * NK + kk) * O + o] = h[((size_t)b * N + j) * O + o] * ss[j];
    }
}

extern "C" void kernel_launch(void* const* d_in, const int* in_sizes, int n_in,
                              void* d_out, int out_size, void* d_ws, size_t ws_size,
                              hipStream_t stream) {
    const float* x     = (const float*)d_in[0];
    const float* attW  = (const float*)d_in[1];
    const float* attB  = (const float*)d_in[2];
    const float* attV  = (const float*)d_in[3];
    const float* pAw   = (const float*)d_in[4];
    const float* pAb   = (const float*)d_in[5];
    const float* pNw   = (const float*)d_in[6];
    const float* pNb   = (const float*)d_in[7];
    const float* bng   = (const float*)d_in[8];
    const float* bnb   = (const float*)d_in[9];
    const float* bnm   = (const float*)d_in[10];
    const float* bnv   = (const float*)d_in[11];
    const float* poolW = (const float*)d_in[12];
    const float* poolB = (const float*)d_in[13];
    float* out = (float*)d_out;

    float* l_ws = (float*)d_ws;                     // B*N*N floats (4 MB)
    float* h_ws = l_ws + (size_t)B * N * N;         // B*N*O floats
    float* s_ws = h_ws + (size_t)B * N * O;         // B*N floats

    aasist_pair_kernel<<<B * 256, 512, 0, stream>>>(x, attW, attB, attV, l_ws);

    aasist_row_kernel<<<B * N, 256, 0, stream>>>(
        x, pAw, pAb, pNw, pNb,
        bng, bnb, bnm, bnv, poolW, poolB, l_ws, h_ws, s_ws);

    aasist_topk_kernel<<<B, 256, 0, stream>>>(h_ws, s_ws, out);
}